// Round 3
// baseline (410.917 us; speedup 1.0000x reference)
//
#include <hip/hip_runtime.h>

typedef short bf16x8 __attribute__((ext_vector_type(8)));
typedef float f32x4 __attribute__((ext_vector_type(4)));
typedef unsigned int u32;
typedef unsigned short u16;

#define NT 32
#define NB 4096
#define ND 32
#define NW 64

// Dopri5 tableau
#define A31 ((float)(3.0/40.0))
#define A32 ((float)(9.0/40.0))
#define A41 ((float)(44.0/45.0))
#define A42 ((float)(-56.0/15.0))
#define A43 ((float)(32.0/9.0))
#define A51 ((float)(19372.0/6561.0))
#define A52 ((float)(-25360.0/2187.0))
#define A53 ((float)(64448.0/6561.0))
#define A54 ((float)(-212.0/729.0))
#define A61 ((float)(9017.0/3168.0))
#define A62 ((float)(-355.0/33.0))
#define A63 ((float)(46732.0/5247.0))
#define A64 ((float)(49.0/176.0))
#define A65 ((float)(-5103.0/18656.0))
#define BB1 ((float)(35.0/384.0))
#define BB3 ((float)(500.0/1113.0))
#define BB4 ((float)(125.0/192.0))
#define BB5 ((float)(-2187.0/6784.0))
#define BB6 ((float)(11.0/84.0))

__device__ __forceinline__ u16 f2bf(float x) {
    u32 u = __float_as_uint(x);
    u = (u + 0x7FFFu + ((u >> 16) & 1u)) >> 16;   // RNE
    return (u16)u;
}
__device__ __forceinline__ u32 pk(float a, float b) {
    return (u32)f2bf(a) | ((u32)f2bf(b) << 16);
}
__device__ __forceinline__ float sp(float x) {      // softplus, numerically stable
    return fmaxf(x, 0.0f) + __logf(1.0f + __expf(-fabsf(x)));
}
__device__ __forceinline__ bf16x8 mk_afrag(const float* p) {
    union { u32 u[4]; bf16x8 v; } r;
    r.u[0] = pk(p[0], p[1]); r.u[1] = pk(p[2], p[3]);
    r.u[2] = pk(p[4], p[5]); r.u[3] = pk(p[6], p[7]);
    return r.v;
}

// LDS tiles: 16 rows x 32 u32 (128B rows). Logical u32 index within a row is
// XOR-swizzled by ((row&7)<<2) so that stride-128B ds_read_b128 column reads
// spread across banks (T2 pattern). Write side uses the same XOR (involution).

__global__ __launch_bounds__(128, 1)
void node_kernel(const float* __restrict__ ts, const float* __restrict__ y0,
                 const float* __restrict__ W1, const float* __restrict__ b1,
                 const float* __restrict__ W2, const float* __restrict__ b2,
                 const float* __restrict__ W3, const float* __restrict__ b3,
                 float* __restrict__ out)
{
    __shared__ __align__(16) u32 ylds[16 * 32];
    __shared__ __align__(16) u32 h1ds[16 * 32];
    __shared__ __align__(16) u32 h2ds[16 * 32];

    const int tid  = threadIdx.x;
    const int w    = tid >> 6;          // wave 0..1
    const int lane = tid & 63;
    const int n    = lane & 15;         // batch col (B-col, D-col — same)
    const int q    = lane >> 4;         // MFMA quad
    const int swz  = (n & 7) << 2;      // u32-index XOR for this row
    const int row0 = blockIdx.x * 16;

    // ---- weight A-fragments (bf16) + biases, one-time ----
    bf16x8 a1[2], a2[2][2], a3[2];
    f32x4 bs1[2], bs2[2], bs3;
    #pragma unroll
    for (int i = 0; i < 2; ++i) {
        const int mt = 2 * w + i;       // hidden m-tile for L1/L2
        a1[i]    = mk_afrag(W1 + (mt * 16 + n) * ND + q * 8);
        a2[i][0] = mk_afrag(W2 + (mt * 16 + n) * NW + q * 8);
        a2[i][1] = mk_afrag(W2 + (mt * 16 + n) * NW + 32 + q * 8);
        bs1[i] = *(const f32x4*)(b1 + mt * 16 + q * 4);
        bs2[i] = *(const f32x4*)(b2 + mt * 16 + q * 4);
    }
    a3[0] = mk_afrag(W3 + (w * 16 + n) * NW + q * 8);        // L3 m-tile = w, full K
    a3[1] = mk_afrag(W3 + (w * 16 + n) * NW + 32 + q * 8);
    bs3 = *(const f32x4*)(b3 + w * 16 + q * 4);

    // ---- RK state: thread owns y[row0+n][d0..d0+3], matches L3 D-layout ----
    const int d0 = w * 16 + q * 4;
    f32x4 y = *(const f32x4*)(y0 + (size_t)(row0 + n) * ND + d0);
    *(f32x4*)(out + (size_t)(row0 + n) * ND + d0) = y;       // ys[0] = y0

    auto writeY = [&](f32x4 v) {
        uint2 p; p.x = pk(v[0], v[1]); p.y = pk(v[2], v[3]);
        *(uint2*)&ylds[n * 32 + (((w * 8 + q * 2)) ^ swz)] = p;
    };
    writeY(y);

    auto evalf = [&](f32x4& kk) {
        __syncthreads();                                     // (1) y_stage ready
        bf16x8 by = *(const bf16x8*)&ylds[n * 32 + ((q * 4) ^ swz)];
        f32x4 u0 = bs1[0], u1 = bs1[1];
        u0 = __builtin_amdgcn_mfma_f32_16x16x32_bf16(a1[0], by, u0, 0, 0, 0);
        u1 = __builtin_amdgcn_mfma_f32_16x16x32_bf16(a1[1], by, u1, 0, 0, 0);
        {
            uint2 p0, p1;
            p0.x = pk(sp(u0[0]), sp(u0[1])); p0.y = pk(sp(u0[2]), sp(u0[3]));
            p1.x = pk(sp(u1[0]), sp(u1[1])); p1.y = pk(sp(u1[2]), sp(u1[3]));
            *(uint2*)&h1ds[n * 32 + (((2 * w + 0) * 8 + q * 2) ^ swz)] = p0;
            *(uint2*)&h1ds[n * 32 + (((2 * w + 1) * 8 + q * 2) ^ swz)] = p1;
        }
        __syncthreads();                                     // (2) h1 ready
        bf16x8 bh0 = *(const bf16x8*)&h1ds[n * 32 + ((q * 4) ^ swz)];
        bf16x8 bh1 = *(const bf16x8*)&h1ds[n * 32 + ((16 + q * 4) ^ swz)];
        f32x4 v0 = bs2[0], v1 = bs2[1];
        v0 = __builtin_amdgcn_mfma_f32_16x16x32_bf16(a2[0][0], bh0, v0, 0, 0, 0);
        v0 = __builtin_amdgcn_mfma_f32_16x16x32_bf16(a2[0][1], bh1, v0, 0, 0, 0);
        v1 = __builtin_amdgcn_mfma_f32_16x16x32_bf16(a2[1][0], bh0, v1, 0, 0, 0);
        v1 = __builtin_amdgcn_mfma_f32_16x16x32_bf16(a2[1][1], bh1, v1, 0, 0, 0);
        {
            uint2 p0, p1;
            p0.x = pk(sp(v0[0]), sp(v0[1])); p0.y = pk(sp(v0[2]), sp(v0[3]));
            p1.x = pk(sp(v1[0]), sp(v1[1])); p1.y = pk(sp(v1[2]), sp(v1[3]));
            *(uint2*)&h2ds[n * 32 + (((2 * w + 0) * 8 + q * 2) ^ swz)] = p0;
            *(uint2*)&h2ds[n * 32 + (((2 * w + 1) * 8 + q * 2) ^ swz)] = p1;
        }
        __syncthreads();                                     // (3) h2 ready
        bf16x8 c0 = *(const bf16x8*)&h2ds[n * 32 + ((q * 4) ^ swz)];
        bf16x8 c1 = *(const bf16x8*)&h2ds[n * 32 + ((16 + q * 4) ^ swz)];
        f32x4 kv = bs3;
        kv = __builtin_amdgcn_mfma_f32_16x16x32_bf16(a3[0], c0, kv, 0, 0, 0);
        kv = __builtin_amdgcn_mfma_f32_16x16x32_bf16(a3[1], c1, kv, 0, 0, 0);
        kk = kv;                                             // k in RK-state layout
    };

    #pragma unroll 1
    for (int iv = 0; iv < NT - 1; ++iv) {
        const float hs = (ts[iv + 1] - ts[iv]) * 0.5f;       // K=2 substeps
        #pragma unroll 1
        for (int sub = 0; sub < 2; ++sub) {
            f32x4 k1, k2, k3, k4, k5, k6;
            evalf(k1);
            writeY(y + hs * (0.2f * k1));
            evalf(k2);
            writeY(y + hs * (A31 * k1 + A32 * k2));
            evalf(k3);
            writeY(y + hs * (A41 * k1 + A42 * k2 + A43 * k3));
            evalf(k4);
            writeY(y + hs * (A51 * k1 + A52 * k2 + A53 * k3 + A54 * k4));
            evalf(k5);
            writeY(y + hs * (A61 * k1 + A62 * k2 + A63 * k3 + A64 * k4 + A65 * k5));
            evalf(k6);
            y = y + hs * (BB1 * k1 + BB3 * k3 + BB4 * k4 + BB5 * k5 + BB6 * k6);
            writeY(y);
        }
        *(f32x4*)(out + ((size_t)(iv + 1) * NB + row0 + n) * ND + d0) = y;
    }

    if (blockIdx.x == 0 && tid == 0) {
        out[(size_t)NT * NB * ND] = 62.0f;                   // num_steps = (T-1)*K
    }
}

extern "C" void kernel_launch(void* const* d_in, const int* in_sizes, int n_in,
                              void* d_out, int out_size, void* d_ws, size_t ws_size,
                              hipStream_t stream) {
    const float* ts = (const float*)d_in[0];
    const float* y0 = (const float*)d_in[1];
    const float* W1 = (const float*)d_in[2];
    const float* b1 = (const float*)d_in[3];
    const float* W2 = (const float*)d_in[4];
    const float* b2 = (const float*)d_in[5];
    const float* W3 = (const float*)d_in[6];
    const float* b3 = (const float*)d_in[7];
    float* out = (float*)d_out;

    node_kernel<<<dim3(NB / 16), dim3(128), 0, stream>>>(ts, y0, W1, b1, W2, b2, W3, b3, out);
}

// Round 4
// 266.431 us; speedup vs baseline: 1.5423x; 1.5423x over previous
//
#include <hip/hip_runtime.h>

typedef short bf16x8 __attribute__((ext_vector_type(8)));
typedef float f32x4 __attribute__((ext_vector_type(4)));
typedef unsigned int u32;

#define NT 32
#define NB 4096
#define ND 32
#define NW 64

// Dopri5 tableau
#define A31 ((float)(3.0/40.0))
#define A32 ((float)(9.0/40.0))
#define A41 ((float)(44.0/45.0))
#define A42 ((float)(-56.0/15.0))
#define A43 ((float)(32.0/9.0))
#define A51 ((float)(19372.0/6561.0))
#define A52 ((float)(-25360.0/2187.0))
#define A53 ((float)(64448.0/6561.0))
#define A54 ((float)(-212.0/729.0))
#define A61 ((float)(9017.0/3168.0))
#define A62 ((float)(-355.0/33.0))
#define A63 ((float)(46732.0/5247.0))
#define A64 ((float)(49.0/176.0))
#define A65 ((float)(-5103.0/18656.0))
#define BB1 ((float)(35.0/384.0))
#define BB3 ((float)(500.0/1113.0))
#define BB4 ((float)(125.0/192.0))
#define BB5 ((float)(-2187.0/6784.0))
#define BB6 ((float)(11.0/84.0))

// Single-instruction RNE pack: D.lo = bf16(a), D.hi = bf16(b)
__device__ __forceinline__ u32 pk(float a, float b) {
    u32 r;
    asm("v_cvt_pk_bf16_f32 %0, %1, %2" : "=v"(r) : "v"(a), "v"(b));
    return r;
}
__device__ __forceinline__ float sp(float x) {      // softplus, numerically stable
    return fmaxf(x, 0.0f) + __logf(1.0f + __expf(-fabsf(x)));
}
__device__ __forceinline__ bf16x8 mk_afrag(const float* p) {
    union { u32 u[4]; bf16x8 v; } r;
    r.u[0] = pk(p[0], p[1]); r.u[1] = pk(p[2], p[3]);
    r.u[2] = pk(p[4], p[5]); r.u[3] = pk(p[6], p[7]);
    return r.v;
}

// LDS tiles: 16 rows x 32 u32 (128B rows), u32 index XOR-swizzled by
// ((row&7)<<2) on both write and read sides (proven correct + low-conflict
// in R3). 4 waves: wave w owns hidden m-tile w for L1/L2. L3 + RK state on
// waves 0-1 only (full-K MFMA -> k stays in registers, no 4th barrier).

__global__ __launch_bounds__(256, 1)
void node_kernel(const float* __restrict__ ts, const float* __restrict__ y0,
                 const float* __restrict__ W1, const float* __restrict__ b1,
                 const float* __restrict__ W2, const float* __restrict__ b2,
                 const float* __restrict__ W3, const float* __restrict__ b3,
                 float* __restrict__ out)
{
    __shared__ __align__(16) u32 ylds[16 * 32];
    __shared__ __align__(16) u32 h1ds[16 * 32];
    __shared__ __align__(16) u32 h2ds[16 * 32];
    __shared__ float hsl[NT];

    const int tid  = threadIdx.x;
    const int w    = tid >> 6;          // wave 0..3
    const int lane = tid & 63;
    const int n    = lane & 15;         // batch col
    const int q    = lane >> 4;         // MFMA quad
    const int swz  = (n & 7) << 2;
    const int row0 = blockIdx.x * 16;

    if (tid < NT - 1) hsl[tid] = (ts[tid + 1] - ts[tid]) * 0.5f;  // K=2 substeps

    // ---- weights: wave w handles hidden m-tile w in L1/L2 ----
    bf16x8 a1   = mk_afrag(W1 + (w * 16 + n) * ND + q * 8);
    bf16x8 a2lo = mk_afrag(W2 + (w * 16 + n) * NW + q * 8);
    bf16x8 a2hi = mk_afrag(W2 + (w * 16 + n) * NW + 32 + q * 8);
    f32x4 bs1 = *(const f32x4*)(b1 + w * 16 + q * 4);
    f32x4 bs2 = *(const f32x4*)(b2 + w * 16 + q * 4);

    // ---- L3 + RK state: waves 0-1 only; thread owns y[row0+n][d0..d0+3] ----
    const int d0 = w * 16 + q * 4;
    bf16x8 a3lo = {}, a3hi = {};
    f32x4 bs3 = {}, y = {};
    if (w < 2) {
        a3lo = mk_afrag(W3 + (w * 16 + n) * NW + q * 8);
        a3hi = mk_afrag(W3 + (w * 16 + n) * NW + 32 + q * 8);
        bs3 = *(const f32x4*)(b3 + w * 16 + q * 4);
        y = *(const f32x4*)(y0 + (size_t)(row0 + n) * ND + d0);
        *(f32x4*)(out + (size_t)(row0 + n) * ND + d0) = y;      // ys[0] = y0
        uint2 p; p.x = pk(y[0], y[1]); p.y = pk(y[2], y[3]);
        *(uint2*)&ylds[n * 32 + ((w * 8 + q * 2) ^ swz)] = p;
    }
    __syncthreads();   // hsl + initial y visible before first hsl read

    auto writeY = [&](f32x4 vv) {      // call only on waves 0-1
        uint2 p; p.x = pk(vv[0], vv[1]); p.y = pk(vv[2], vv[3]);
        *(uint2*)&ylds[n * 32 + ((w * 8 + q * 2) ^ swz)] = p;
    };

    auto evalf = [&](f32x4& kk) {
        __syncthreads();                                     // (1) y_stage ready
        bf16x8 by = *(const bf16x8*)&ylds[n * 32 + ((q * 4) ^ swz)];
        f32x4 u = bs1;
        u = __builtin_amdgcn_mfma_f32_16x16x32_bf16(a1, by, u, 0, 0, 0);
        {
            uint2 p; p.x = pk(sp(u[0]), sp(u[1])); p.y = pk(sp(u[2]), sp(u[3]));
            *(uint2*)&h1ds[n * 32 + ((w * 8 + q * 2) ^ swz)] = p;
        }
        __syncthreads();                                     // (2) h1 ready
        bf16x8 bh0 = *(const bf16x8*)&h1ds[n * 32 + ((q * 4) ^ swz)];
        bf16x8 bh1 = *(const bf16x8*)&h1ds[n * 32 + ((16 + q * 4) ^ swz)];
        f32x4 v = bs2;
        v = __builtin_amdgcn_mfma_f32_16x16x32_bf16(a2lo, bh0, v, 0, 0, 0);
        v = __builtin_amdgcn_mfma_f32_16x16x32_bf16(a2hi, bh1, v, 0, 0, 0);
        {
            uint2 p; p.x = pk(sp(v[0]), sp(v[1])); p.y = pk(sp(v[2]), sp(v[3]));
            *(uint2*)&h2ds[n * 32 + ((w * 8 + q * 2) ^ swz)] = p;
        }
        __syncthreads();                                     // (3) h2 ready
        if (w < 2) {
            bf16x8 c0 = *(const bf16x8*)&h2ds[n * 32 + ((q * 4) ^ swz)];
            bf16x8 c1 = *(const bf16x8*)&h2ds[n * 32 + ((16 + q * 4) ^ swz)];
            f32x4 kv = bs3;
            kv = __builtin_amdgcn_mfma_f32_16x16x32_bf16(a3lo, c0, kv, 0, 0, 0);
            kv = __builtin_amdgcn_mfma_f32_16x16x32_bf16(a3hi, c1, kv, 0, 0, 0);
            kk = kv;                                         // k in RK-state layout
        }
    };

    #pragma unroll 1
    for (int iv = 0; iv < NT - 1; ++iv) {
        const float hs = hsl[iv];       // LDS read, latency hidden under evalf
        #pragma unroll 1
        for (int sub = 0; sub < 2; ++sub) {
            f32x4 k1, k2, k3, k4, k5, k6;
            evalf(k1);
            if (w < 2) writeY(y + hs * (0.2f * k1));
            evalf(k2);
            if (w < 2) writeY(y + hs * (A31 * k1 + A32 * k2));
            evalf(k3);
            if (w < 2) writeY(y + hs * (A41 * k1 + A42 * k2 + A43 * k3));
            evalf(k4);
            if (w < 2) writeY(y + hs * (A51 * k1 + A52 * k2 + A53 * k3 + A54 * k4));
            evalf(k5);
            if (w < 2) writeY(y + hs * (A61 * k1 + A62 * k2 + A63 * k3 + A64 * k4 + A65 * k5));
            evalf(k6);
            if (w < 2) {
                y = y + hs * (BB1 * k1 + BB3 * k3 + BB4 * k4 + BB5 * k5 + BB6 * k6);
                writeY(y);
            }
        }
        if (w < 2) {
            *(f32x4*)(out + ((size_t)(iv + 1) * NB + row0 + n) * ND + d0) = y;
        }
    }

    if (blockIdx.x == 0 && tid == 0) {
        out[(size_t)NT * NB * ND] = 62.0f;                   // num_steps = (T-1)*K
    }
}

extern "C" void kernel_launch(void* const* d_in, const int* in_sizes, int n_in,
                              void* d_out, int out_size, void* d_ws, size_t ws_size,
                              hipStream_t stream) {
    const float* ts = (const float*)d_in[0];
    const float* y0 = (const float*)d_in[1];
    const float* W1 = (const float*)d_in[2];
    const float* b1 = (const float*)d_in[3];
    const float* W2 = (const float*)d_in[4];
    const float* b2 = (const float*)d_in[5];
    const float* W3 = (const float*)d_in[6];
    const float* b3 = (const float*)d_in[7];
    float* out = (float*)d_out;

    node_kernel<<<dim3(NB / 16), dim3(256), 0, stream>>>(ts, y0, W1, b1, W2, b2, W3, b3, out);
}